// Round 7
// baseline (27.169 us; speedup 1.0000x reference)
//
#include <hip/hip_runtime.h>

// CorrLookup: RAFT-style correlation-pyramid lookup.
// B=8, H=96, W=256, N=B*H*W=196608, R=4, K=9, 4 levels, Wi = 256>>lvl.
// Round-7: occupancy A/B. One thread per (pixel, level); blockIdx.y = level
// (wave-uniform). 3072 blocks -> 48 waves/CU offered (vs 12 at 1 thread/px),
// capped at 32 by HW. Load pattern is the proven R6 one: 3 aligned float4
// chunks + 1 address-redirected scalar tail, all clamped & unconditional
// (no exec-mask predication), zeros-padding applied by value select.

#define RADIUS 4
#define KTAPS 9

__global__ __launch_bounds__(256) void corr_lookup_kernel(
    const float* __restrict__ corr0,
    const float* __restrict__ corr1,
    const float* __restrict__ corr2,
    const float* __restrict__ corr3,
    const float* __restrict__ flow,
    float* __restrict__ out,
    int HW, int N)
{
    int n = blockIdx.x * blockDim.x + threadIdx.x;
    if (n >= N) return;
    const int lvl = blockIdx.y;          // wave-uniform level

    int b   = n / HW;          // batch
    int rem = n - b * HW;      // h*W + w within the image

    // flow layout: (B, 2, H, W); channel 0 = disparity
    float disp = flow[(size_t)b * 2 * HW + rem];

    const float* base = (lvl == 0) ? corr0 : (lvl == 1) ? corr1
                      : (lvl == 2) ? corr2 : corr3;
    const int Wi = 256 >> lvl;
    const int Wc = Wi >> 2;                          // row length in float4

    float t  = disp * (1.0f / (float)(1 << lvl));    // exact pow2 scale
    float fb = floorf(t);
    float w  = t - fb;           // shared fractional weight for all 9 taps
    int   ib = (int)fb;

    int s  = ib - RADIUS;        // first tap index (may be negative)
    int o  = s & 3;              // tap-0 offset within first chunk
    int c0 = s >> 2;             // floor(s/4): first aligned chunk

    const float* rowp  = base + (size_t)n * (size_t)Wi;
    const float4* row4 = (const float4*)rowp;

    // 3 aligned chunks cover elements 0..11 of the 13-element window;
    // element 12 (needed only when o==3) comes from a scalar tail load
    // whose address is redirected to element 11 when o<3 (same line).
    int cA = min(max(c0 + 0, 0), Wc - 1);
    int cB = min(max(c0 + 1, 0), Wc - 1);
    int cC = min(max(c0 + 2, 0), Wc - 1);
    float4 q0 = row4[cA];
    float4 q1 = row4[cB];
    float4 q2 = row4[cC];
    int tail_idx = (c0 << 2) + ((o == 3) ? 12 : 11);
    tail_idx = min(max(tail_idx, 0), Wi - 1);
    float tail = rowp[tail_idx];

    float e[13] = {q0.x, q0.y, q0.z, q0.w,
                   q1.x, q1.y, q1.z, q1.w,
                   q2.x, q2.y, q2.z, q2.w, tail};

    bool o0 = (o == 0), o1 = (o == 1), o2 = (o == 2);

    float v[KTAPS + 1];
#pragma unroll
    for (int j = 0; j <= KTAPS; ++j) {
        float sel = o0 ? e[j + 0] : o1 ? e[j + 1] : o2 ? e[j + 2] : e[j + 3];
        v[j] = ((unsigned)(s + j) < (unsigned)Wi) ? sel : 0.0f;
    }

    // out layout: (B, 36, H, W)
    size_t ob = (size_t)b * 36 * HW + (size_t)(lvl * KTAPS) * HW + (size_t)rem;
#pragma unroll
    for (int k = 0; k < KTAPS; ++k) {
        float val = (1.0f - w) * v[k] + w * v[k + 1];
        out[ob + (size_t)k * HW] = val;
    }
}

extern "C" void kernel_launch(void* const* d_in, const int* in_sizes, int n_in,
                              void* d_out, int out_size, void* d_ws, size_t ws_size,
                              hipStream_t stream)
{
    const float* corr0 = (const float*)d_in[0];
    const float* corr1 = (const float*)d_in[1];
    const float* corr2 = (const float*)d_in[2];
    const float* corr3 = (const float*)d_in[3];
    const float* flow  = (const float*)d_in[4];
    float* out = (float*)d_out;

    const int N  = in_sizes[4] / 2;   // flow is (B,2,H,W)
    const int B  = 8;
    const int HW = N / B;             // 96*256 = 24576

    dim3 block(256);
    dim3 grid((N + 255) / 256, 4);    // y = pyramid level (uniform per block)
    hipLaunchKernelGGL(corr_lookup_kernel, grid, block, 0, stream,
                       corr0, corr1, corr2, corr3, flow, out, HW, N);
}